// Round 3
// baseline (7285.298 us; speedup 1.0000x reference)
//
#include <hip/hip_runtime.h>
#include <hip/hip_bf16.h>

#define V 10000
#define E 128
#define H1 128
#define H2 64
#define D 64
#define T 512
#define B 256
#define MAXLEN 30
#define SOS 1
#define EOS 2
#define BGS 16         // batch elements per pred task
#define NVB 40         // v-blocks in pred ((V+255)/256)
#define KB1 4          // batch elements per K1 block
#define NB1 (B/KB1)    // 64 K1 blocks

// converted-weight layout offsets (floats) inside ws
#define O_EMB   0
#define O_WIH1  1280000      // + V*E
#define O_WHH1  1378304      // + 512*192
#define O_BIH1  1443840      // + 512*128
#define O_BHH1  1444352      // + 512
#define O_WIH2  1444864      // + 512
#define O_WHH2  1477632      // + 256*128
#define O_BIH2  1494016      // + 256*64
#define O_BHH2  1494272      // + 256
#define O_WQ    1494528      // + 256
#define O_BQ    1498624      // + 64*64
#define O_WP    1498688      // + 64
#define O_BP    2778688      // + 10000*128
#define TOTALW  2788688      // + 10000

typedef unsigned long long u64;

__device__ __forceinline__ float b2f(__hip_bfloat16 x){ return __bfloat162float(x); }
__device__ __forceinline__ float sigf(float x){ return 1.f/(1.f + expf(-x)); }
__device__ __forceinline__ float4 ldf4(const float* p){
  float4 r; __builtin_memcpy(&r, (const void*)p, 16); return r;
}
__device__ __forceinline__ float dot4f(const float* x, float4 w){
  return x[0]*w.x + x[1]*w.y + x[2]*w.z + x[3]*w.w;
}

// ---------------------------------------------------------------------------
// kdtype: bf16 vs fp32 detection (unchanged, verified).
// ---------------------------------------------------------------------------
__global__ void kdtype(const void* __restrict__ probe, int* __restrict__ flagp){
  const int tid = threadIdx.x;                 // 64 threads
  const unsigned w = ((const unsigned*)probe)[tid];
  const unsigned e = (w >> 7) & 0xFFu;
  const bool inband = (e >= 0x60u) && (e <= 0x7Eu);
  const u64 m = __ballot(inband);
  if (tid == 0) flagp[0] = (m == 0xFFFFFFFFFFFFFFFFull) ? 1 : 0;
}

// ---------------------------------------------------------------------------
// kcvt: convert all weight tensors to fp32 into ws (unchanged, verified).
// ---------------------------------------------------------------------------
__global__ __launch_bounds__(256) void kcvt(
    const void* s_emb, const void* s_wih1, const void* s_whh1,
    const void* s_bih1, const void* s_bhh1, const void* s_wih2,
    const void* s_whh2, const void* s_bih2, const void* s_bhh2,
    const void* s_wq, const void* s_bq, const void* s_wp, const void* s_bp,
    float* __restrict__ dst, const int* __restrict__ flagp)
{
  const int idx = blockIdx.x * 256 + threadIdx.x;
  if (idx >= TOTALW) return;
  const int flag = flagp[0];
  const void* src; int off;
  if      (idx < O_WIH1){ src = s_emb;  off = idx - O_EMB;  }
  else if (idx < O_WHH1){ src = s_wih1; off = idx - O_WIH1; }
  else if (idx < O_BIH1){ src = s_whh1; off = idx - O_WHH1; }
  else if (idx < O_BHH1){ src = s_bih1; off = idx - O_BIH1; }
  else if (idx < O_WIH2){ src = s_bhh1; off = idx - O_BHH1; }
  else if (idx < O_WHH2){ src = s_wih2; off = idx - O_WIH2; }
  else if (idx < O_BIH2){ src = s_whh2; off = idx - O_WHH2; }
  else if (idx < O_BHH2){ src = s_bih2; off = idx - O_BIH2; }
  else if (idx < O_WQ)  { src = s_bhh2; off = idx - O_BHH2; }
  else if (idx < O_BQ)  { src = s_wq;   off = idx - O_WQ;   }
  else if (idx < O_WP)  { src = s_bq;   off = idx - O_BQ;   }
  else if (idx < O_BP)  { src = s_wp;   off = idx - O_WP;   }
  else                  { src = s_bp;   off = idx - O_BP;   }
  dst[idx] = flag ? b2f(((const __hip_bfloat16*)src)[off])
                  : ((const float*)src)[off];
}

// ---------------------------------------------------------------------------
// ktrans: enc_key/enc_val (T,B,D) -> fp32 (B,T,D) (unchanged, verified).
// ---------------------------------------------------------------------------
__global__ __launch_bounds__(256) void ktrans(
    const void* __restrict__ enc_key, const void* __restrict__ enc_val,
    float* __restrict__ encTk, float* __restrict__ encTv,
    const int* __restrict__ flagp)
{
  const int b = blockIdx.x;
  const int tid = threadIdx.x;
  const int flag = flagp[0];
  const int d = tid & 63, tq = tid >> 6;
  if (flag){
    const __hip_bfloat16* bk = (const __hip_bfloat16*)enc_key;
    const __hip_bfloat16* bv = (const __hip_bfloat16*)enc_val;
    for (int tt = tq; tt < T; tt += 4){
      encTk[((size_t)b*T + tt)*D + d] = b2f(bk[((size_t)tt*B + b)*D + d]);
      encTv[((size_t)b*T + tt)*D + d] = b2f(bv[((size_t)tt*B + b)*D + d]);
    }
  } else {
    const float* fk = (const float*)enc_key;
    const float* fv = (const float*)enc_val;
    for (int tt = tq; tt < T; tt += 4){
      encTk[((size_t)b*T + tt)*D + d] = fk[((size_t)tt*B + b)*D + d];
      encTv[((size_t)b*T + tt)*D + d] = fv[((size_t)tt*B + b)*D + d];
    }
  }
}

// ---------------------------------------------------------------------------
// K1: fused decoder step minus pred. 64 blocks x 512 threads; block owns 4 b's
// for everything: argmax -> LSTM1 -> LSTM2 -> query -> attention -> xvec.
// h1/c1/h2/c2/ctx are block-private across steps (no double-buffering).
// Weight rows are streamed from L2 once per block with 4x batch reuse.
// ---------------------------------------------------------------------------
__global__ __launch_bounds__(512) void K1(
    int t,
    const float* __restrict__ wts,
    const float* __restrict__ encTk, const float* __restrict__ encTv,
    const int* __restrict__ mask,
    float* __restrict__ h1g,   // [B][H1]
    float* __restrict__ c1g,   // [B][H1]
    float* __restrict__ h2g,   // [B][H2]
    float* __restrict__ c2g,   // [B][H2]
    float* __restrict__ ctxg,  // [B][D]
    float* __restrict__ xvec,  // [B][H2+D]
    const float* __restrict__ candv, const int* __restrict__ candi)
{
  const int bid = blockIdx.x;      // 0..63
  const int tid = threadIdx.x;     // 0..511
  const int bA  = bid * KB1;
  const int wv  = tid >> 6;        // wave 0..7
  const int lane = tid & 63;

  __shared__ __align__(16) float xs[KB1*324];   // [bi][0..319] LSTM1 input
  __shared__ __align__(16) float x2s[KB1*196];  // [bi][0..191] LSTM2 input
  __shared__ float g1s[512*5];                  // LSTM1 gates [r][bi] pad5
  __shared__ float g2s[256*5];                  // LSTM2 gates [r][bi] pad5
  __shared__ float h2s[KB1*64];
  __shared__ float q_s[KB1*64];
  __shared__ float wv_s[KB1*512];               // masked softmax weights
  __shared__ float cpart[8*64];                 // context partials per wave
  __shared__ float redmax[8], redsum[8], inv_s[KB1];
  __shared__ int tok_s[KB1];

  // ---- phase 0: token argmax (waves 0..3) | x2s h2prev fill (waves 4..7) ----
  if (wv < KB1){
    const int b = bA + wv;
    float mv = -__builtin_inff(); int mi = 0x7FFFFFFF;
    if (t > 0){
      if (lane < NVB){ mv = candv[b*NVB + lane]; mi = candi[b*NVB + lane]; }
      #pragma unroll
      for (int off = 32; off > 0; off >>= 1){
        float ov = __shfl_down(mv, off); int oi = __shfl_down(mi, off);
        if (ov > mv || (ov == mv && oi < mi)){ mv = ov; mi = oi; }
      }
      if (lane == 0) tok_s[wv] = mi;
    } else {
      if (lane == 0) tok_s[wv] = SOS;
    }
  } else {
    const int idx = tid - 256;              // 0..255
    const int bi = idx >> 6, j = idx & 63;
    x2s[bi*196 + 128 + j] = (t == 0) ? 0.f : h2g[(size_t)(bA + bi)*H2 + j];
  }
  __syncthreads();

  // ---- phase 1: xs = [emb(128) | ctx(64) | h1prev(128)] per b ----
  if (tid < 320){
    const int k = tid;
    #pragma unroll
    for (int bi = 0; bi < KB1; ++bi){
      const int b = bA + bi;
      const int tok = tok_s[bi];
      float x;
      if (k < E)          x = (tok == EOS) ? 0.f : wts[O_EMB + (size_t)tok*E + k];
      else if (k < E + D) x = (t == 0) ? 0.f : ctxg[(size_t)b*D + (k - E)];
      else                x = (t == 0) ? 0.f : h1g[(size_t)b*H1 + (k - (E + D))];
      xs[bi*324 + k] = x;
    }
  }
  __syncthreads();

  // ---- phase 2: LSTM1 gates, thread = gate-row r (512), acc over 4 b ----
  {
    const int r = tid;
    const float bias = wts[O_BIH1 + r] + wts[O_BHH1 + r];
    float a0 = bias, a1 = bias, a2 = bias, a3 = bias;
    #pragma unroll 4
    for (int k4 = 0; k4 < 80; ++k4){
      float4 w;
      if (k4 < 48) w = ldf4(wts + O_WIH1 + (size_t)r*(E+D) + k4*4);
      else         w = ldf4(wts + O_WHH1 + (size_t)r*H1 + (k4-48)*4);
      const float4 xa = ldf4(xs + 0*324 + k4*4);
      const float4 xb = ldf4(xs + 1*324 + k4*4);
      const float4 xc = ldf4(xs + 2*324 + k4*4);
      const float4 xd = ldf4(xs + 3*324 + k4*4);
      a0 += xa.x*w.x + xa.y*w.y + xa.z*w.z + xa.w*w.w;
      a1 += xb.x*w.x + xb.y*w.y + xb.z*w.z + xb.w*w.w;
      a2 += xc.x*w.x + xc.y*w.y + xc.z*w.z + xc.w*w.w;
      a3 += xd.x*w.x + xd.y*w.y + xd.z*w.z + xd.w*w.w;
    }
    g1s[r*5 + 0] = a0; g1s[r*5 + 1] = a1;
    g1s[r*5 + 2] = a2; g1s[r*5 + 3] = a3;
  }
  __syncthreads();

  // ---- phase 3: LSTM1 update (128 units x 4 b), h1 -> x2s + global ----
  {
    const int u = tid >> 2, bi = tid & 3;   // all 512 threads
    const int b = bA + bi;
    const float gi = sigf (g1s[(u      )*5 + bi]);
    const float gf = sigf (g1s[(128 + u)*5 + bi]);
    const float gg = tanhf(g1s[(256 + u)*5 + bi]);
    const float go = sigf (g1s[(384 + u)*5 + bi]);
    const float cold = (t == 0) ? 0.f : c1g[(size_t)b*H1 + u];
    const float cn = gf*cold + gi*gg;
    const float hn = go*tanhf(cn);
    c1g[(size_t)b*H1 + u] = cn;
    h1g[(size_t)b*H1 + u] = hn;
    x2s[bi*196 + u] = hn;
  }
  __syncthreads();

  // ---- phase 4: LSTM2 gates, thread = (row r, b-half), acc over 2 b ----
  {
    const int r = tid & 255, bh = tid >> 8; // bh in {0,1}
    const float bias = wts[O_BIH2 + r] + wts[O_BHH2 + r];
    float a0 = bias, a1 = bias;
    const float* x0 = x2s + (bh*2    )*196;
    const float* x1 = x2s + (bh*2 + 1)*196;
    #pragma unroll 4
    for (int k4 = 0; k4 < 48; ++k4){
      float4 w;
      if (k4 < 32) w = ldf4(wts + O_WIH2 + (size_t)r*H1 + k4*4);
      else         w = ldf4(wts + O_WHH2 + (size_t)r*H2 + (k4-32)*4);
      const float4 xa = ldf4(x0 + k4*4);
      const float4 xb = ldf4(x1 + k4*4);
      a0 += xa.x*w.x + xa.y*w.y + xa.z*w.z + xa.w*w.w;
      a1 += xb.x*w.x + xb.y*w.y + xb.z*w.z + xb.w*w.w;
    }
    g2s[r*5 + bh*2]     = a0;
    g2s[r*5 + bh*2 + 1] = a1;
  }
  __syncthreads();

  // ---- phase 5: LSTM2 update (64 units x 4 b) -> h2s, xvec, globals ----
  if (tid < 256){
    const int u = tid >> 2, bi = tid & 3;
    const int b = bA + bi;
    const float gi = sigf (g2s[(u      )*5 + bi]);
    const float gf = sigf (g2s[(64  + u)*5 + bi]);
    const float gg = tanhf(g2s[(128 + u)*5 + bi]);
    const float go = sigf (g2s[(192 + u)*5 + bi]);
    const float cold = (t == 0) ? 0.f : c2g[(size_t)b*H2 + u];
    const float cn = gf*cold + gi*gg;
    const float hn = go*tanhf(cn);
    c2g[(size_t)b*H2 + u] = cn;
    h2g[(size_t)b*H2 + u] = hn;
    h2s[bi*64 + u] = hn;
    xvec[(size_t)b*(H2 + D) + u] = hn;
  }
  __syncthreads();

  // ---- phase 6: query (64 dims x 4 b) ----
  if (tid < 256){
    const int d = tid & 63, bi = tid >> 6;
    const float* wr = wts + O_WQ + (size_t)d*H2;
    float acc = wts[O_BQ + d];
    #pragma unroll
    for (int kk = 0; kk < H2/4; ++kk) acc += dot4f(h2s + bi*64 + kk*4, ldf4(wr + kk*4));
    q_s[bi*64 + d] = acc;
  }
  __syncthreads();

  // ---- phase 7: attention energies; wave pair (bi, half) covers 512 t2 ----
  const int abi = wv & 3, half = wv >> 2;
  const int ab = bA + abi;
  float e0 = 0.f, e1 = 0.f, e2 = 0.f, e3 = 0.f;
  {
    const int t2b = half*256;
    const float* k0 = encTk + ((size_t)ab*T + t2b + 0*64 + lane)*D;
    const float* k1 = encTk + ((size_t)ab*T + t2b + 1*64 + lane)*D;
    const float* k2 = encTk + ((size_t)ab*T + t2b + 2*64 + lane)*D;
    const float* k3 = encTk + ((size_t)ab*T + t2b + 3*64 + lane)*D;
    #pragma unroll
    for (int kk = 0; kk < D/4; ++kk){
      const float4 q4 = ldf4(q_s + abi*64 + kk*4);
      e0 += dot4f((const float*)&q4, ldf4(k0 + kk*4)) * 0.f + q4.x*k0[kk*4] + q4.y*k0[kk*4+1] + q4.z*k0[kk*4+2] + q4.w*k0[kk*4+3];
      e1 += q4.x*k1[kk*4] + q4.y*k1[kk*4+1] + q4.z*k1[kk*4+2] + q4.w*k1[kk*4+3];
      e2 += q4.x*k2[kk*4] + q4.y*k2[kk*4+1] + q4.z*k2[kk*4+2] + q4.w*k2[kk*4+3];
      e3 += q4.x*k3[kk*4] + q4.y*k3[kk*4+1] + q4.z*k3[kk*4+2] + q4.w*k3[kk*4+3];
    }
  }
  {
    float me = fmaxf(fmaxf(e0, e1), fmaxf(e2, e3));
    #pragma unroll
    for (int off = 32; off > 0; off >>= 1) me = fmaxf(me, __shfl_xor(me, off));
    if (lane == 0) redmax[wv] = me;
  }
  __syncthreads();

  // ---- phase 8: masked exp weights + per-wave sum ----
  {
    const float emax = fmaxf(redmax[abi], redmax[abi + 4]);
    const int t2b = half*256;
    const int m0 = mask[ab*T + t2b + 0*64 + lane];
    const int m1 = mask[ab*T + t2b + 1*64 + lane];
    const int m2 = mask[ab*T + t2b + 2*64 + lane];
    const int m3 = mask[ab*T + t2b + 3*64 + lane];
    const float w0 = m0 ? expf(e0 - emax) : 0.f;
    const float w1 = m1 ? expf(e1 - emax) : 0.f;
    const float w2 = m2 ? expf(e2 - emax) : 0.f;
    const float w3 = m3 ? expf(e3 - emax) : 0.f;
    wv_s[abi*512 + t2b + 0*64 + lane] = w0;
    wv_s[abi*512 + t2b + 1*64 + lane] = w1;
    wv_s[abi*512 + t2b + 2*64 + lane] = w2;
    wv_s[abi*512 + t2b + 3*64 + lane] = w3;
    float sm = w0 + w1 + w2 + w3;
    #pragma unroll
    for (int off = 32; off > 0; off >>= 1) sm += __shfl_xor(sm, off);
    if (lane == 0) redsum[wv] = sm;
  }
  __syncthreads();

  // ---- phase 9: context partial (each wave: 256 t for its b-half) ----
  {
    if (half == 0 && lane == 0)
      inv_s[abi] = 1.f / fmaxf(redsum[abi] + redsum[abi + 4], 2e-30f);
    const float* vb2 = encTv + (size_t)ab*T*D + lane;
    float acc = 0.f;
    const int t0 = half*256;
    #pragma unroll 8
    for (int tt = t0; tt < t0 + 256; ++tt)
      acc += wv_s[abi*512 + tt] * vb2[(size_t)tt*D];
    cpart[wv*64 + lane] = acc;
  }
  __syncthreads();

  // ---- phase 10: combine context halves, write ctx + xvec ----
  if (wv < KB1){
    const int b = bA + wv;
    const float cv = (cpart[wv*64 + lane] + cpart[(wv + 4)*64 + lane]) * inv_s[wv];
    ctxg[(size_t)b*D + lane] = cv;
    xvec[(size_t)b*(H2 + D) + H2 + lane] = cv;
  }
}

// ---------------------------------------------------------------------------
// kC: pred = xvec @ wp.T + bp, fused store + per-(b, v-block) argmax candidate
// (verified round-2 kernel; BGS raised 8 -> 16 to halve wp re-reads).
// grid (NVB x B/BGS), 256 threads.
// ---------------------------------------------------------------------------
__global__ __launch_bounds__(256) void kC(
    int t,
    const float* __restrict__ wp_f,
    const float* __restrict__ bp_f,
    const float* __restrict__ xvec,
    void* __restrict__ outv,
    float* __restrict__ candv, int* __restrict__ candi,
    const int* __restrict__ flagp)
{
  const int tid = threadIdx.x;
  const int vb = blockIdx.x;
  const int v = vb * 256 + tid;
  const int bg = blockIdx.y;
  const int flagb = flagp[0];
  const bool valid = v < V;
  const int vc = valid ? v : 0;
  const float* wrow = wp_f + (size_t)vc*(H2 + D);
  const float* xp = xvec + (size_t)bg*BGS*(H2 + D);

  float acc[BGS];
  #pragma unroll
  for (int i = 0; i < BGS; ++i) acc[i] = 0.f;

  #pragma unroll
  for (int kk = 0; kk < (H2 + D)/4; ++kk){
    const float4 w = ldf4(wrow + kk*4);
    #pragma unroll
    for (int i = 0; i < BGS; ++i){
      const float* x = xp + i*(H2 + D) + kk*4;
      acc[i] += x[0]*w.x + x[1]*w.y + x[2]*w.z + x[3]*w.w;
    }
  }

  const float bias = valid ? bp_f[vc] : 0.f;
  #pragma unroll
  for (int i = 0; i < BGS; ++i){
    acc[i] += bias;
    if (valid){
      const size_t oi = ((size_t)(bg*BGS + i)*MAXLEN + t)*V + v;
      if (flagb) ((__hip_bfloat16*)outv)[oi] = __float2bfloat16(acc[i]);
      else       ((float*)outv)[oi] = acc[i];
    }
  }

  // per-b (val, idx) max with first-index tie-break: wave shuffle -> LDS -> ws
  __shared__ float lv[4][BGS];
  __shared__ int   li[4][BGS];
  const int lane = tid & 63, wid = tid >> 6;
  #pragma unroll
  for (int i = 0; i < BGS; ++i){
    float mv = valid ? acc[i] : -__builtin_inff();
    int   mi = valid ? v : 0x7FFFFFFF;
    for (int off = 32; off > 0; off >>= 1){
      float ov = __shfl_down(mv, off);
      int   oi = __shfl_down(mi, off);
      if (ov > mv || (ov == mv && oi < mi)){ mv = ov; mi = oi; }
    }
    if (lane == 0){ lv[wid][i] = mv; li[wid][i] = mi; }
  }
  __syncthreads();
  if (tid < BGS){
    float mv = lv[0][tid]; int mi = li[0][tid];
    #pragma unroll
    for (int w2 = 1; w2 < 4; ++w2){
      float ov = lv[w2][tid]; int oi = li[w2][tid];
      if (ov > mv || (ov == mv && oi < mi)){ mv = ov; mi = oi; }
    }
    const int b = bg*BGS + tid;
    candv[b*NVB + vb] = mv;
    candi[b*NVB + vb] = mi;
  }
}

// ---------------------------------------------------------------------------
extern "C" void kernel_launch(void* const* d_in, const int* in_sizes, int n_in,
                              void* d_out, int out_size, void* d_ws, size_t ws_size,
                              hipStream_t stream)
{
  const void* enc_key = d_in[0];
  const void* enc_val = d_in[1];
  const int*  mask    = (const int*)d_in[2];
  const void* emb     = d_in[3];
  const void* w_ih1   = d_in[4];
  const void* w_hh1   = d_in[5];
  const void* b_ih1   = d_in[6];
  const void* b_hh1   = d_in[7];
  const void* w_ih2   = d_in[8];
  const void* w_hh2   = d_in[9];
  const void* b_ih2   = d_in[10];
  const void* b_hh2   = d_in[11];
  const void* wq      = d_in[12];
  const void* bq      = d_in[13];
  const void* wp      = d_in[14];
  const void* bp      = d_in[15];

  // ws layout: [flag 16f][wts TOTALW][h1g][c1g][h2g][c2g][ctx][xvec]
  //            [candv][candi][encTk][encTv]
  float* wsf  = (float*)d_ws;
  int*  flagp = (int*)wsf;
  float* wts  = wsf + 16;
  float* h1g   = wts + TOTALW;
  float* c1g   = h1g + B*H1;
  float* h2g   = c1g + B*H1;
  float* c2g   = h2g + B*H2;
  float* ctxg  = c2g + B*H2;
  float* xvec  = ctxg + B*D;
  float* candv = xvec + B*(H2 + D);
  int*   candi = (int*)(candv + B*NVB);
  float* encTk = (float*)(candi + B*NVB);
  float* encTv = encTk + (size_t)B*T*D;

  kdtype<<<dim3(1), dim3(64), 0, stream>>>(b_ih1, flagp);
  kcvt<<<dim3((TOTALW + 255)/256), dim3(256), 0, stream>>>(
      emb, w_ih1, w_hh1, b_ih1, b_hh1, w_ih2, w_hh2, b_ih2, b_hh2,
      wq, bq, wp, bp, wts, flagp);
  ktrans<<<dim3(B), dim3(256), 0, stream>>>(enc_key, enc_val, encTk, encTv, flagp);

  for (int t = 0; t < MAXLEN; ++t){
    K1<<<dim3(NB1), dim3(512), 0, stream>>>(
        t, wts, encTk, encTv, mask,
        h1g, c1g, h2g, c2g, ctxg, xvec, candv, candi);
    kC<<<dim3(NVB, B/BGS), dim3(256), 0, stream>>>(
        t, wts + O_WP, wts + O_BP, xvec, d_out, candv, candi, flagp);
  }
}